// Round 10
// baseline (610.308 us; speedup 1.0000x reference)
//
#include <hip/hip_runtime.h>

#define BN_EPS 1e-5f
#define ELLW 48      // slot 0 = count, slots 4..47 = neighbor ids (16B-aligned), cap 44 >> max deg ~33
#define BSH2 11      // bucket = dst >> 11  (2048 nodes per bucket)
#define NPB 2048
#define MAXBK 160    // compile-time bound on bucket count (N <= 327680)
#define BCAP2 26624  // per-bucket edge capacity (mean ~20.4K, +43 sigma)

// ---------------- detect int64 vs int32 edge_index ----------------
__global__ void k_detect(const unsigned int* __restrict__ ei, int* __restrict__ flag) {
    int t = threadIdx.x;                 // 64 threads, one wave
    unsigned int v = ei[2 * t + 1];      // odd words: int64 high-halves (==0) or real int32 values
    unsigned long long mask = __ballot(v != 0);
    if (t == 0) flag[0] = (mask == 0ULL) ? 1 : 0;   // 1 => int64
}

// ---------------- shared-memory overlays for the fused kernel ----------------
struct FfnS {
    float sW1c[4 * 25 * 28];   // [kc][j][k'] padded rows of 28
    float sW2p[100 * 28];      // [k][j2]     padded rows of 28
    float sWcp[25 * 32];       // [k][j]      stride 32, cols 25..31 zero
    float sB1[100], sS1[100];
    float sB2[32], sS2[32];
};
struct PartS {
    int hist[MAXBK];
    int cur[MAXBK];
    int gbase[MAXBK];
    int locstart[MAXBK + 1];
    int sc[256];
    int stage[1024];
};

// ---------------- fused: FFN (BN-folded, +Wc1 dense, UNSCALED out) ∥ edge partition ----------------
// Blocks [0, nFfn): FFN, 2 nodes per 4-lane group (M-block x2, halves LDS weight traffic).
// Blocks [nFfn, ...): block-grouped partition by dst>>11 (independent of FFN).
__global__ __launch_bounds__(256) void k_ffnpart(
    const float* __restrict__ x,
    const float* __restrict__ W1, const float* __restrict__ b1,
    const float* __restrict__ g1, const float* __restrict__ be1,
    const float* __restrict__ m1, const float* __restrict__ v1,
    const float* __restrict__ W2, const float* __restrict__ b2,
    const float* __restrict__ g2, const float* __restrict__ be2,
    const float* __restrict__ m2, const float* __restrict__ v2,
    const float* __restrict__ Wc1,
    float* __restrict__ T,
    const int* __restrict__ ei, const int* __restrict__ flag,
    int* __restrict__ gcnt, int* __restrict__ bdata,
    int nFfn, int N, int E)
{
    __shared__ char smem_raw[sizeof(FfnS) > sizeof(PartS) ? sizeof(FfnS) : sizeof(PartS)];
    int t = threadIdx.x;

    if ((int)blockIdx.x < nFfn) {
        FfnS& S = *reinterpret_cast<FfnS*>(smem_raw);
        if (t < 100) {
            float s = g1[t] * rsqrtf(v1[t] + BN_EPS);
            S.sS1[t] = s;
            S.sB1[t] = (b1[t] - m1[t]) * s + be1[t];
        }
        if (t >= 128 && t < 153) {
            int u = t - 128;
            float s = g2[u] * rsqrtf(v2[u] + BN_EPS);
            S.sS2[u] = s;
            S.sB2[u] = (b2[u] - m2[u]) * s + be2[u];
        }
        __syncthreads();
        for (int q = t; q < 2500; q += 256) {
            int j = q / 100, k = q % 100;
            int kc = k / 25, kk = k % 25;
            S.sW1c[(kc * 25 + j) * 28 + kk] = W1[q] * S.sS1[k];
        }
        for (int q = t; q < 2500; q += 256) {
            int k = q / 25, j2 = q % 25;
            S.sW2p[k * 28 + j2] = W2[q] * S.sS2[j2];
        }
        for (int q = t; q < 800; q += 256) {
            int k = q >> 5, j = q & 31;
            S.sWcp[q] = (j < 25) ? Wc1[k * 25 + j] : 0.0f;
        }
        __syncthreads();

        int g = t >> 2;        // group (0..63), 2 nodes each
        int l = t & 3;         // lane role within group
        int n0 = ((int)blockIdx.x * 64 + g) * 2;
        if (n0 >= N) return;
        bool two = (n0 + 1 < N);
        int nB = two ? n0 + 1 : n0;

        float xiA[25], xiB[25];
#pragma unroll
        for (int j = 0; j < 25; ++j) xiA[j] = x[(size_t)n0 * 25 + j];
#pragma unroll
        for (int j = 0; j < 25; ++j) xiB[j] = x[(size_t)nB * 25 + j];

        // stage 1: hidden chunk l*25..l*25+24 for both nodes (shared weight reads)
        float hmA[25], hmB[25];
#pragma unroll
        for (int kk = 0; kk < 25; ++kk) { hmA[kk] = S.sB1[l * 25 + kk]; hmB[kk] = hmA[kk]; }
#pragma unroll
        for (int j = 0; j < 25; ++j) {
            float xa = xiA[j], xb = xiB[j];
            const float* __restrict__ wr = &S.sW1c[(l * 25 + j) * 28];
#pragma unroll
            for (int kk = 0; kk < 25; ++kk) {
                float w = wr[kk];
                hmA[kk] += xa * w;
                hmB[kk] += xb * w;
            }
        }

        // stage 2: partial h0 from own 25 hidden units, both nodes
        float hA[25], hB[25];
#pragma unroll
        for (int j2 = 0; j2 < 25; ++j2) { hA[j2] = 0.0f; hB[j2] = 0.0f; }
#pragma unroll
        for (int kk = 0; kk < 25; ++kk) {
            float ra = fmaxf(hmA[kk], 0.0f);
            float rb = fmaxf(hmB[kk], 0.0f);
            const float* __restrict__ w2r = &S.sW2p[(l * 25 + kk) * 28];
#pragma unroll
            for (int j2 = 0; j2 < 25; ++j2) {
                float w = w2r[j2];
                hA[j2] += ra * w;
                hB[j2] += rb * w;
            }
        }
        // reduce partials across the 4-lane group; bias after reduction
#pragma unroll
        for (int j2 = 0; j2 < 25; ++j2) {
            hA[j2] += __shfl_xor(hA[j2], 1);
            hA[j2] += __shfl_xor(hA[j2], 2);
            hA[j2] += S.sB2[j2];
            hB[j2] += __shfl_xor(hB[j2], 1);
            hB[j2] += __shfl_xor(hB[j2], 2);
            hB[j2] += S.sB2[j2];
        }

        // stage 3: output slice l*8..l*8+7, UNSCALED (dinv applied in L1 gather)
        float oA[8], oB[8];
#pragma unroll
        for (int jj = 0; jj < 8; ++jj) { oA[jj] = 0.0f; oB[jj] = 0.0f; }
#pragma unroll
        for (int k = 0; k < 25; ++k) {
            float ha = hA[k], hb = hB[k];
            const float* __restrict__ wr = &S.sWcp[k * 32 + l * 8];
#pragma unroll
            for (int jj = 0; jj < 8; ++jj) {
                float w = wr[jj];
                oA[jj] += ha * w;
                oB[jj] += hb * w;
            }
        }
        float4* TA = (float4*)(T + (size_t)n0 * 32 + l * 8);
        TA[0] = make_float4(oA[0], oA[1], oA[2], oA[3]);
        TA[1] = make_float4(oA[4], oA[5], oA[6], oA[7]);
        if (two) {
            float4* TB = (float4*)(T + (size_t)(n0 + 1) * 32 + l * 8);
            TB[0] = make_float4(oB[0], oB[1], oB[2], oB[3]);
            TB[1] = make_float4(oB[4], oB[5], oB[6], oB[7]);
        }
    } else {
        PartS& S = *reinterpret_cast<PartS*>(smem_raw);
        int blockBase = ((int)blockIdx.x - nFfn) * 1024;
        int blockCnt = E - blockBase; if (blockCnt > 1024) blockCnt = 1024; if (blockCnt < 0) blockCnt = 0;

        for (int i = t; i < MAXBK; i += 256) S.hist[i] = 0;
        __syncthreads();

        bool w64 = (flag[0] != 0);
        int e = blockBase + t * 4;
        int s[4], d[4];
        int cnt = 0;
        if (e < E) {
            cnt = E - e; if (cnt > 4) cnt = 4;
            if (cnt == 4) {
                if (w64) {
                    const int4* ps = (const int4*)(ei + (size_t)2 * e);
                    int4 a = ps[0], b = ps[1];
                    s[0] = a.x; s[1] = a.z; s[2] = b.x; s[3] = b.z;
                    const int4* pd = (const int4*)(ei + (size_t)2 * ((size_t)E + e));
                    int4 c = pd[0], f = pd[1];
                    d[0] = c.x; d[1] = c.z; d[2] = f.x; d[3] = f.z;
                } else {
                    int4 a = *(const int4*)(ei + e);
                    s[0] = a.x; s[1] = a.y; s[2] = a.z; s[3] = a.w;
                    int4 c = *(const int4*)(ei + (size_t)E + e);
                    d[0] = c.x; d[1] = c.y; d[2] = c.z; d[3] = c.w;
                }
            } else {
                for (int i = 0; i < cnt; ++i) {
                    if (w64) { s[i] = ei[(size_t)2 * (e + i)]; d[i] = ei[(size_t)2 * ((size_t)E + e + i)]; }
                    else     { s[i] = ei[e + i];               d[i] = ei[(size_t)E + e + i]; }
                }
            }
        }
        int bk[4], pk[4];
        for (int i = 0; i < cnt; ++i) {
            bk[i] = d[i] >> BSH2;
            pk[i] = (s[i] << BSH2) | (d[i] & (NPB - 1));
            atomicAdd(&S.hist[bk[i]], 1);
        }
        __syncthreads();

        // inclusive scan over MAXBK (padded to 256)
        S.sc[t] = (t < MAXBK) ? S.hist[t] : 0;
        __syncthreads();
        for (int off = 1; off < 256; off <<= 1) {
            int xv = (t >= off) ? S.sc[t - off] : 0;
            __syncthreads();
            S.sc[t] += xv;
            __syncthreads();
        }
        if (t < MAXBK) {
            S.locstart[t] = S.sc[t] - S.hist[t];
            S.cur[t] = S.sc[t] - S.hist[t];
            if (S.hist[t] > 0) S.gbase[t] = atomicAdd(&gcnt[t], S.hist[t]);
        }
        if (t == 255) S.locstart[MAXBK] = S.sc[MAXBK - 1];
        __syncthreads();

        // stage grouped by bucket
        for (int i = 0; i < cnt; ++i) {
            int p = atomicAdd(&S.cur[bk[i]], 1);
            S.stage[p] = pk[i];
        }
        __syncthreads();

        // copy groups out contiguously
        for (int sIdx = t; sIdx < blockCnt; sIdx += 256) {
            int lo = 0, hi = MAXBK;
            while (hi - lo > 1) {
                int mid = (lo + hi) >> 1;
                if (S.locstart[mid] <= sIdx) lo = mid; else hi = mid;
            }
            int gp = S.gbase[lo] + (sIdx - S.locstart[lo]);
            if (gp < BCAP2) bdata[(size_t)lo * BCAP2 + gp] = S.stage[sIdx];
        }
    }
}

// ---------------- pass 2: one block per bucket; LDS slot alloc; write ELL + count + dinv ----------------
__global__ __launch_bounds__(256) void k_ell2(
    const int* __restrict__ gcnt, const int* __restrict__ bdata,
    int* __restrict__ ell, float* __restrict__ dinv, int N)
{
    __shared__ int lcnt[NPB];
    int b = blockIdx.x;
    int t = threadIdx.x;
    for (int i = t; i < NPB; i += 256) lcnt[i] = 0;
    __syncthreads();
    int base = b << BSH2;
    int cnt = min(gcnt[b], BCAP2);
    const int* __restrict__ bd = bdata + (size_t)b * BCAP2;
    for (int i = t; i < cnt; i += 256) {
        int v = bd[i];
        int dl = v & (NPB - 1);
        int src = v >> BSH2;                      // v < 2^30, arithmetic shift fine
        int pos = atomicAdd(&lcnt[dl], 1);
        if (pos < ELLW - 4)
            ell[(size_t)(base + dl) * ELLW + 4 + pos] = src;
    }
    __syncthreads();
    for (int i = t; i < NPB; i += 256) {
        int n = base + i;
        if (n < N) {
            int c = lcnt[i];
            ell[(size_t)n * ELLW] = c;
            dinv[n] = 1.0f / sqrtf((float)(c + 1));   // +1 self-loop
        }
    }
}

// ---------------- fused layer: float4 gather (ELL) + finalize + dense + scale ----------------
// LPN = lanes/node, each lane owns 4 features. SI = input stride (floats, mult of 4).
// SDV: Tin is unscaled -> multiply each gathered row by dinv[src] (L1 only).
template <int DI, int SI, int DO, int LPN, bool SDV>
__global__ __launch_bounds__(256) void k_layer(
    const int* __restrict__ ell,
    const float* __restrict__ dinv, const float* __restrict__ bias,   // bias: [DI]
    const float* __restrict__ W,                                      // [DI x DO]
    const float* __restrict__ Tin, float* __restrict__ Tout, int N)
{
    constexpr int SI4 = SI / 4;
    constexpr int DO4 = DO / 4;
    constexpr int PAD = LPN * 4;
    __shared__ float sW[DI * DO];
    __shared__ float sB[PAD];
    int t = threadIdx.x;
    for (int i = t; i < DI * DO; i += 256) sW[i] = W[i];
    for (int i = t; i < PAD; i += 256) sB[i] = (i < DI) ? bias[i] : 0.0f;
    __syncthreads();

    int g = t / LPN;
    int j = t % LPN;
    int n = blockIdx.x * (256 / LPN) + g;
    int nc = (n < N) ? n : (N - 1);
    const int* __restrict__ row = ell + (size_t)nc * ELLW;
    int dg = min(row[0], ELLW - 4);
    if (n >= N) dg = 0;
    float dv = dinv[nc];
    const float4* __restrict__ T4 = (const float4*)Tin;

    float4 a0 = T4[(size_t)nc * SI4 + j];   // self-loop term
    if (SDV) { a0.x *= dv; a0.y *= dv; a0.z *= dv; a0.w *= dv; }
    float4 a1 = make_float4(0.f, 0.f, 0.f, 0.f);
    float4 a2 = a1, a3 = a1;
    const int4* __restrict__ rowv = (const int4*)(row + 4);
    int k = 0;
    for (; k + 3 < dg; k += 4) {
        int4 s4 = rowv[k >> 2];
        float4 v0 = T4[(size_t)s4.x * SI4 + j];
        float4 v1 = T4[(size_t)s4.y * SI4 + j];
        float4 v2 = T4[(size_t)s4.z * SI4 + j];
        float4 v3 = T4[(size_t)s4.w * SI4 + j];
        if (SDV) {
            float d0 = dinv[s4.x], d1 = dinv[s4.y], d2 = dinv[s4.z], d3 = dinv[s4.w];
            a0.x += d0 * v0.x; a0.y += d0 * v0.y; a0.z += d0 * v0.z; a0.w += d0 * v0.w;
            a1.x += d1 * v1.x; a1.y += d1 * v1.y; a1.z += d1 * v1.z; a1.w += d1 * v1.w;
            a2.x += d2 * v2.x; a2.y += d2 * v2.y; a2.z += d2 * v2.z; a2.w += d2 * v2.w;
            a3.x += d3 * v3.x; a3.y += d3 * v3.y; a3.z += d3 * v3.z; a3.w += d3 * v3.w;
        } else {
            a0.x += v0.x; a0.y += v0.y; a0.z += v0.z; a0.w += v0.w;
            a1.x += v1.x; a1.y += v1.y; a1.z += v1.z; a1.w += v1.w;
            a2.x += v2.x; a2.y += v2.y; a2.z += v2.z; a2.w += v2.w;
            a3.x += v3.x; a3.y += v3.y; a3.z += v3.z; a3.w += v3.w;
        }
    }
    for (; k < dg; ++k) {
        int sidx = row[4 + k];
        float4 v = T4[(size_t)sidx * SI4 + j];
        float dd = SDV ? dinv[sidx] : 1.0f;
        a0.x += dd * v.x; a0.y += dd * v.y; a0.z += dd * v.z; a0.w += dd * v.w;
    }
    float ar[4];
    ar[0] = fmaxf(dv * (a0.x + a1.x + a2.x + a3.x) + sB[4 * j + 0], 0.0f);
    ar[1] = fmaxf(dv * (a0.y + a1.y + a2.y + a3.y) + sB[4 * j + 1], 0.0f);
    ar[2] = fmaxf(dv * (a0.z + a1.z + a2.z + a3.z) + sB[4 * j + 2], 0.0f);
    ar[3] = fmaxf(dv * (a0.w + a1.w + a2.w + a3.w) + sB[4 * j + 3], 0.0f);

    // dense via intra-group shuffle all-to-all (k-th activation = comp k&3 of lane base+(k>>2))
    int lane = t & 63;
    int base = lane - j;
    int jo = (j < DO4) ? j : 0;
    const float4* __restrict__ sW4 = (const float4*)sW;
    float4 o = make_float4(0.f, 0.f, 0.f, 0.f);
#pragma unroll
    for (int k2 = 0; k2 < DI; ++k2) {
        float av = __shfl(ar[k2 & 3], base + (k2 >> 2));
        float4 w = sW4[k2 * DO4 + jo];
        o.x += av * w.x; o.y += av * w.y; o.z += av * w.z; o.w += av * w.w;
    }
    if (n < N && j < DO4)
        ((float4*)Tout)[(size_t)n * DO4 + j] =
            make_float4(dv * o.x, dv * o.y, dv * o.z, dv * o.w);
}

// ---------------- final layer: float4 gather + finalize only (dim 4, 1 lane/node) ----------------
__global__ __launch_bounds__(256) void k_final(
    const int* __restrict__ ell,
    const float* __restrict__ dinv, const float* __restrict__ bias,
    const float* __restrict__ Tin, float* __restrict__ Tout, int N)
{
    int n = blockIdx.x * 256 + threadIdx.x;
    if (n >= N) return;
    const int* __restrict__ row = ell + (size_t)n * ELLW;
    int dg = min(row[0], ELLW - 4);
    float dv = dinv[n];
    const float4* __restrict__ T4 = (const float4*)Tin;

    float4 a0 = T4[n];
    float4 a1 = make_float4(0.f, 0.f, 0.f, 0.f);
    float4 a2 = a1, a3 = a1;
    const int4* __restrict__ rowv = (const int4*)(row + 4);
    int k = 0;
    for (; k + 3 < dg; k += 4) {
        int4 s4 = rowv[k >> 2];
        float4 v0 = T4[s4.x], v1 = T4[s4.y], v2 = T4[s4.z], v3 = T4[s4.w];
        a0.x += v0.x; a0.y += v0.y; a0.z += v0.z; a0.w += v0.w;
        a1.x += v1.x; a1.y += v1.y; a1.z += v1.z; a1.w += v1.w;
        a2.x += v2.x; a2.y += v2.y; a2.z += v2.z; a2.w += v2.w;
        a3.x += v3.x; a3.y += v3.y; a3.z += v3.z; a3.w += v3.w;
    }
    for (; k < dg; ++k) {
        float4 v = T4[row[4 + k]];
        a0.x += v.x; a0.y += v.y; a0.z += v.z; a0.w += v.w;
    }
    float4 b = *(const float4*)bias;
    ((float4*)Tout)[n] = make_float4(
        fmaxf(dv * (a0.x + a1.x + a2.x + a3.x) + b.x, 0.0f),
        fmaxf(dv * (a0.y + a1.y + a2.y + a3.y) + b.y, 0.0f),
        fmaxf(dv * (a0.z + a1.z + a2.z + a3.z) + b.z, 0.0f),
        fmaxf(dv * (a0.w + a1.w + a2.w + a3.w) + b.w, 0.0f));
}

// ---------------- FC: [1000,1200] @ [1200,4] + bias ----------------
__global__ __launch_bounds__(256) void k_fc(
    const float* __restrict__ H, const float* __restrict__ Wfc,
    const float* __restrict__ bfc, float* __restrict__ out)
{
    int r = blockIdx.x;          // 1000 rows
    int t = threadIdx.x;
    float p0 = 0.f, p1 = 0.f, p2 = 0.f, p3 = 0.f;
    for (int k = t; k < 1200; k += 256) {
        float h = H[(size_t)r * 1200 + k];
        p0 += h * Wfc[k * 4 + 0];
        p1 += h * Wfc[k * 4 + 1];
        p2 += h * Wfc[k * 4 + 2];
        p3 += h * Wfc[k * 4 + 3];
    }
#pragma unroll
    for (int off = 32; off > 0; off >>= 1) {
        p0 += __shfl_down(p0, off);
        p1 += __shfl_down(p1, off);
        p2 += __shfl_down(p2, off);
        p3 += __shfl_down(p3, off);
    }
    __shared__ float red[4][4];
    int w = t >> 6, lane = t & 63;
    if (lane == 0) { red[w][0] = p0; red[w][1] = p1; red[w][2] = p2; red[w][3] = p3; }
    __syncthreads();
    if (t < 4) {
        float s = red[0][t] + red[1][t] + red[2][t] + red[3][t];
        out[r * 4 + t] = s + bfc[t];
    }
}

// ---------------------------------------------------------------------------
extern "C" void kernel_launch(void* const* d_in, const int* in_sizes, int n_in,
                              void* d_out, int out_size, void* d_ws, size_t ws_size,
                              hipStream_t stream) {
    const float* x   = (const float*)d_in[0];
    const int*   ei  = (const int*)d_in[1];
    const float* W1  = (const float*)d_in[2];
    const float* b1  = (const float*)d_in[3];
    const float* g1  = (const float*)d_in[4];
    const float* be1 = (const float*)d_in[5];
    const float* m1  = (const float*)d_in[6];
    const float* v1  = (const float*)d_in[7];
    const float* W2  = (const float*)d_in[8];
    const float* b2  = (const float*)d_in[9];
    const float* g2  = (const float*)d_in[10];
    const float* be2 = (const float*)d_in[11];
    const float* m2  = (const float*)d_in[12];
    const float* v2  = (const float*)d_in[13];
    const float* Wc1 = (const float*)d_in[14];
    const float* bc1 = (const float*)d_in[15];
    const float* Wc2 = (const float*)d_in[16];
    const float* bc2 = (const float*)d_in[17];
    const float* Wc3 = (const float*)d_in[18];
    const float* bc3 = (const float*)d_in[19];
    const float* Wc4 = (const float*)d_in[20];
    const float* bc4 = (const float*)d_in[21];
    const float* Wc5 = (const float*)d_in[22];
    const float* bc5 = (const float*)d_in[23];
    const float* Wfc = (const float*)d_in[24];
    const float* bfc = (const float*)d_in[25];

    const int N = in_sizes[0] / 25;          // 300000
    const int E = in_sizes[1] / 2;           // 3000000
    const int NBUCK = (N + NPB - 1) >> BSH2; // 147

    // ---- workspace layout (256B aligned) ----
    char* ws = (char*)d_ws;
    size_t off = 0;
    auto alloc = [&](size_t bytes) { size_t o = off; off += (bytes + 255) & ~(size_t)255; return o; };
    size_t o_flag = alloc(256);
    size_t o_gcnt = alloc((size_t)MAXBK * 4);
    size_t o_dinv = alloc((size_t)N * 4);
    size_t o_ell  = alloc((size_t)N * ELLW * 4);   // 57.6 MB
    size_t o_A = alloc((size_t)N * 32 * 4);        // stride-32 buffer (38.4 MB)
    size_t o_B = alloc((size_t)N * 16 * 4);        // stride-16 buffer (19.2 MB)
    (void)alloc(4096);                             // tail pad

    int*   flag = (int*)(ws + o_flag);
    int*   gcnt = (int*)(ws + o_gcnt);
    float* dinv = (float*)(ws + o_dinv);
    int*   ell  = (int*)(ws + o_ell);
    float* A = (float*)(ws + o_A);
    float* B_ = (float*)(ws + o_B);
    int*   bdata = (int*)B_;  // 17.0 MB alias in B_ (19.2 MB): consumed by k_ell2 before L1 writes B_.
                              // NOT in A: part runs concurrently with ffn writing A.

    const int B = 256;
    int gN = (N + B - 1) / B;
    int gF = (N + 127) / 128;                // ffn blocks: 128 nodes/block (2 per 4-lane group)
    int gP = (E + 1023) / 1024;              // part blocks

    k_detect<<<1, 64, 0, stream>>>((const unsigned int*)ei, flag);
    hipMemsetAsync(gcnt, 0, (size_t)MAXBK * 4, stream);
    // fused FFN ∥ partition (independent work, block-split)
    k_ffnpart<<<gF + gP, B, 0, stream>>>(x, W1, b1, g1, be1, m1, v1, W2, b2, g2, be2, m2, v2,
                                         Wc1, A, ei, flag, gcnt, bdata, gF, N, E);
    k_ell2<<<NBUCK, B, 0, stream>>>(gcnt, bdata, ell, dinv, N);

    // L1: gather(25,s32, dinv[src]-scaled) + bc1 + Wc2 -> B (dim 16)
    k_layer<25, 32, 16, 8, true><<<(N * 8 + B - 1) / B, B, 0, stream>>>(ell, dinv, bc1, Wc2, A, B_, N);
    // L2: gather(16) + bc2 + Wc3 -> A (dim 16)
    k_layer<16, 16, 16, 4, false><<<(N * 4 + B - 1) / B, B, 0, stream>>>(ell, dinv, bc2, Wc3, B_, A, N);
    // L3: gather(16) + bc3 + Wc4 -> B (dim 8)
    k_layer<16, 16, 8, 4, false><<<(N * 4 + B - 1) / B, B, 0, stream>>>(ell, dinv, bc3, Wc4, A, B_, N);
    // L4: gather(8) + bc4 + Wc5 -> A (dim 4)
    k_layer<8, 8, 4, 2, false><<<(N * 2 + B - 1) / B, B, 0, stream>>>(ell, dinv, bc4, Wc5, B_, A, N);
    // L5: gather(4) + bc5 + relu -> B (dim 4, final node features)
    k_final<<<gN, B, 0, stream>>>(ell, dinv, bc5, A, B_, N);
    // FC
    k_fc<<<1000, B, 0, stream>>>(B_, Wfc, bfc, (float*)d_out);
}

// Round 11
// 577.662 us; speedup vs baseline: 1.0565x; 1.0565x over previous
//
#include <hip/hip_runtime.h>

#define BN_EPS 1e-5f
#define ELLW 48      // slot 0 = count, slots 4..47 = neighbor ids (16B-aligned), cap 44 >> max deg ~33
#define BSH2 11      // bucket = dst >> 11  (2048 nodes per bucket)
#define NPB 2048
#define MAXBK 160    // compile-time bound on bucket count (N <= 327680)
#define BCAP2 26624  // per-bucket edge capacity (mean ~20.4K, +43 sigma)

// ---------------- detect int64 vs int32 edge_index ----------------
__global__ void k_detect(const unsigned int* __restrict__ ei, int* __restrict__ flag) {
    int t = threadIdx.x;                 // 64 threads, one wave
    unsigned int v = ei[2 * t + 1];      // odd words: int64 high-halves (==0) or real int32 values
    unsigned long long mask = __ballot(v != 0);
    if (t == 0) flag[0] = (mask == 0ULL) ? 1 : 0;   // 1 => int64
}

// ---------------- pass 1: block-grouped partition by dst>>11 ----------------
__global__ __launch_bounds__(256) void k_part(
    const int* __restrict__ ei, const int* __restrict__ flag,
    int* __restrict__ gcnt, int* __restrict__ bdata, int E)
{
    __shared__ int hist[MAXBK];
    __shared__ int cur[MAXBK];
    __shared__ int gbase[MAXBK];
    __shared__ int locstart[MAXBK + 1];
    __shared__ int sc[256];
    __shared__ int stage[1024];

    int t = threadIdx.x;
    int blockBase = blockIdx.x * 1024;
    int blockCnt = E - blockBase; if (blockCnt > 1024) blockCnt = 1024; if (blockCnt < 0) blockCnt = 0;

    for (int i = t; i < MAXBK; i += 256) hist[i] = 0;
    __syncthreads();

    bool w64 = (flag[0] != 0);
    int e = blockBase + t * 4;
    int s[4], d[4];
    int cnt = 0;
    if (e < E) {
        cnt = E - e; if (cnt > 4) cnt = 4;
        if (cnt == 4) {
            if (w64) {
                const int4* ps = (const int4*)(ei + (size_t)2 * e);
                int4 a = ps[0], b = ps[1];
                s[0] = a.x; s[1] = a.z; s[2] = b.x; s[3] = b.z;
                const int4* pd = (const int4*)(ei + (size_t)2 * ((size_t)E + e));
                int4 c = pd[0], f = pd[1];
                d[0] = c.x; d[1] = c.z; d[2] = f.x; d[3] = f.z;
            } else {
                int4 a = *(const int4*)(ei + e);
                s[0] = a.x; s[1] = a.y; s[2] = a.z; s[3] = a.w;
                int4 c = *(const int4*)(ei + (size_t)E + e);
                d[0] = c.x; d[1] = c.y; d[2] = c.z; d[3] = c.w;
            }
        } else {
            for (int i = 0; i < cnt; ++i) {
                if (w64) { s[i] = ei[(size_t)2 * (e + i)]; d[i] = ei[(size_t)2 * ((size_t)E + e + i)]; }
                else     { s[i] = ei[e + i];               d[i] = ei[(size_t)E + e + i]; }
            }
        }
    }
    int bk[4], pk[4];
    for (int i = 0; i < cnt; ++i) {
        bk[i] = d[i] >> BSH2;
        pk[i] = (s[i] << BSH2) | (d[i] & (NPB - 1));
        atomicAdd(&hist[bk[i]], 1);
    }
    __syncthreads();

    // inclusive scan over MAXBK (padded to 256)
    sc[t] = (t < MAXBK) ? hist[t] : 0;
    __syncthreads();
    for (int off = 1; off < 256; off <<= 1) {
        int x = (t >= off) ? sc[t - off] : 0;
        __syncthreads();
        sc[t] += x;
        __syncthreads();
    }
    if (t < MAXBK) {
        locstart[t] = sc[t] - hist[t];
        cur[t] = sc[t] - hist[t];
        if (hist[t] > 0) gbase[t] = atomicAdd(&gcnt[t], hist[t]);
    }
    if (t == 255) locstart[MAXBK] = sc[MAXBK - 1];
    __syncthreads();

    // stage grouped by bucket
    for (int i = 0; i < cnt; ++i) {
        int p = atomicAdd(&cur[bk[i]], 1);
        stage[p] = pk[i];
    }
    __syncthreads();

    // copy groups out contiguously
    for (int sIdx = t; sIdx < blockCnt; sIdx += 256) {
        int lo = 0, hi = MAXBK;
        while (hi - lo > 1) {
            int mid = (lo + hi) >> 1;
            if (locstart[mid] <= sIdx) lo = mid; else hi = mid;
        }
        int g = gbase[lo] + (sIdx - locstart[lo]);
        if (g < BCAP2) bdata[(size_t)lo * BCAP2 + g] = stage[sIdx];
    }
}

// ---------------- pass 2: one block per bucket; LDS slot alloc; write ELL + count + dinv ----------------
__global__ __launch_bounds__(256) void k_ell2(
    const int* __restrict__ gcnt, const int* __restrict__ bdata,
    int* __restrict__ ell, float* __restrict__ dinv, int N)
{
    __shared__ int lcnt[NPB];
    int b = blockIdx.x;
    int t = threadIdx.x;
    for (int i = t; i < NPB; i += 256) lcnt[i] = 0;
    __syncthreads();
    int base = b << BSH2;
    int cnt = min(gcnt[b], BCAP2);
    const int* __restrict__ bd = bdata + (size_t)b * BCAP2;
    for (int i = t; i < cnt; i += 256) {
        int v = bd[i];
        int dl = v & (NPB - 1);
        int src = v >> BSH2;                      // v < 2^30, arithmetic shift fine
        int pos = atomicAdd(&lcnt[dl], 1);
        if (pos < ELLW - 4)
            ell[(size_t)(base + dl) * ELLW + 4 + pos] = src;
    }
    __syncthreads();
    for (int i = t; i < NPB; i += 256) {
        int n = base + i;
        if (n < N) {
            int c = lcnt[i];
            ell[(size_t)n * ELLW] = c;
            dinv[n] = 1.0f / sqrtf((float)(c + 1));   // +1 self-loop
        }
    }
}

// ---------------- prep: fold BN scales + (W2'@Wc1) off the hot path ----------------
// prep layout: [0,2800): W1f [kc*25+j][28];  [2800,5600): W2c [k][28];
//              [5600,5700): B1f;  [5704,5736): bvec (b2''@Wc1, pad 32)
__global__ __launch_bounds__(256) void k_prep(
    const float* __restrict__ W1, const float* __restrict__ b1,
    const float* __restrict__ g1, const float* __restrict__ be1,
    const float* __restrict__ m1, const float* __restrict__ v1,
    const float* __restrict__ W2, const float* __restrict__ b2,
    const float* __restrict__ g2, const float* __restrict__ be2,
    const float* __restrict__ m2, const float* __restrict__ v2,
    const float* __restrict__ Wc1, float* __restrict__ prep)
{
    __shared__ float s1[100], bb1[100], s2[25], bb2[25], wc[625];
    int t = threadIdx.x;
    if (t < 100) {
        float s = g1[t] * rsqrtf(v1[t] + BN_EPS);
        s1[t] = s; bb1[t] = (b1[t] - m1[t]) * s + be1[t];
    }
    if (t >= 128 && t < 153) {
        int u = t - 128;
        float s = g2[u] * rsqrtf(v2[u] + BN_EPS);
        s2[u] = s; bb2[u] = (b2[u] - m2[u]) * s + be2[u];
    }
    for (int q = t; q < 625; q += 256) wc[q] = Wc1[q];
    __syncthreads();
    for (int q = t; q < 2800; q += 256) {
        int row = q / 28, kk = q % 28;        // row = kc*25+j
        int kc = row / 25, j = row % 25;
        prep[q] = (kk < 25) ? W1[j * 100 + kc * 25 + kk] * s1[kc * 25 + kk] : 0.0f;
    }
    for (int q = t; q < 2800; q += 256) {
        int k = q / 28, j = q % 28;
        float acc = 0.0f;
        if (j < 25)
            for (int m = 0; m < 25; ++m) acc += W2[k * 25 + m] * s2[m] * wc[m * 25 + j];
        prep[2800 + q] = acc;
    }
    if (t < 100) prep[5600 + t] = bb1[t];
    if (t >= 128 && t < 160) {
        int j = t - 128;
        float acc = 0.0f;
        if (j < 25)
            for (int m = 0; m < 25; ++m) acc += bb2[m] * wc[m * 25 + j];
        prep[5704 + j] = acc;
    }
}

// ---------------- fused FFN (2-stage, prefolded) + dinv scale; out stride 32 ----------------
// 4 lanes per node, 2 nodes per group (M-block x2): lane l owns hidden chunk l*25..l*25+24.
// Stage 2 produces PARTIAL o[25] (linear, no relu after BN2) -> slice-wise shfl reduce.
__global__ __launch_bounds__(256, 3) void k_ffn(
    const float* __restrict__ prep, const float* __restrict__ x,
    const float* __restrict__ dinv, float* __restrict__ T, int N)
{
    __shared__ float sW1[2800];
    __shared__ float sW2c[2800];
    __shared__ float sB1[100];
    __shared__ float sBv[32];
    int t = threadIdx.x;
    for (int q = t; q < 2800; q += 256) sW1[q] = prep[q];
    for (int q = t; q < 2800; q += 256) sW2c[q] = prep[2800 + q];
    if (t < 100) sB1[t] = prep[5600 + t];
    if (t >= 128 && t < 160) sBv[t - 128] = prep[5704 + (t - 128)];
    __syncthreads();

    int g = t >> 2, l = t & 3;
    int n0 = ((int)blockIdx.x * 64 + g) * 2;
    if (n0 >= N) return;
    bool two = (n0 + 1 < N);
    int n1 = two ? n0 + 1 : n0;

    float xiA[25], xiB[25];
#pragma unroll
    for (int j = 0; j < 25; ++j) xiA[j] = x[(size_t)n0 * 25 + j];
#pragma unroll
    for (int j = 0; j < 25; ++j) xiB[j] = x[(size_t)n1 * 25 + j];

    // stage 1: hidden chunk l*25..l*25+24 for both nodes (shared weight reads)
    float hmA[25], hmB[25];
#pragma unroll
    for (int kk = 0; kk < 25; ++kk) { hmA[kk] = sB1[l * 25 + kk]; hmB[kk] = hmA[kk]; }
#pragma unroll
    for (int j = 0; j < 25; ++j) {
        float xa = xiA[j], xb = xiB[j];
        const float* __restrict__ wr = &sW1[(l * 25 + j) * 28];
#pragma unroll
        for (int kk = 0; kk < 25; ++kk) {
            float w = wr[kk];
            hmA[kk] += xa * w;
            hmB[kk] += xb * w;
        }
    }

    // stage 2: partial o (over own hidden chunk) through folded W2c
    float oA[25], oB[25];
#pragma unroll
    for (int j = 0; j < 25; ++j) { oA[j] = 0.0f; oB[j] = 0.0f; }
#pragma unroll
    for (int kk = 0; kk < 25; ++kk) {
        float ra = fmaxf(hmA[kk], 0.0f);
        float rb = fmaxf(hmB[kk], 0.0f);
        const float* __restrict__ wr = &sW2c[(l * 25 + kk) * 28];
#pragma unroll
        for (int j = 0; j < 25; ++j) {
            float w = wr[j];
            oA[j] += ra * w;
            oB[j] += rb * w;
        }
    }

    // slice-wise reduce across the 4-lane group; lane l keeps slice l (static indices only)
    float dvA = dinv[n0], dvB = dinv[n1];
    float outA[8], outB[8];
#pragma unroll
    for (int jj = 0; jj < 8; ++jj) { outA[jj] = 0.0f; outB[jj] = 0.0f; }
#pragma unroll
    for (int s = 0; s < 4; ++s) {
#pragma unroll
        for (int jj = 0; jj < 8; ++jj) {
            constexpr int dummy = 0; (void)dummy;
            int j = s * 8 + jj;
            if (j < 25) {
                float va = oA[j];
                va += __shfl_xor(va, 1); va += __shfl_xor(va, 2);
                float vb = oB[j];
                vb += __shfl_xor(vb, 1); vb += __shfl_xor(vb, 2);
                if (l == s) {
                    outA[jj] = (va + sBv[j]) * dvA;
                    outB[jj] = (vb + sBv[j]) * dvB;
                }
            }
        }
    }

    float4* TA = (float4*)(T + (size_t)n0 * 32 + l * 8);
    TA[0] = make_float4(outA[0], outA[1], outA[2], outA[3]);
    TA[1] = make_float4(outA[4], outA[5], outA[6], outA[7]);
    if (two) {
        float4* TB = (float4*)(T + (size_t)n1 * 32 + l * 8);
        TB[0] = make_float4(outB[0], outB[1], outB[2], outB[3]);
        TB[1] = make_float4(outB[4], outB[5], outB[6], outB[7]);
    }
}

// ---------------- fused layer: float4 gather (ELL) + finalize + dense + scale ----------------
// LPN = lanes/node, each lane owns 4 features. SI = input stride (floats, mult of 4).
template <int DI, int SI, int DO, int LPN>
__global__ __launch_bounds__(256) void k_layer(
    const int* __restrict__ ell,
    const float* __restrict__ dinv, const float* __restrict__ bias,   // bias: [DI]
    const float* __restrict__ W,                                      // [DI x DO]
    const float* __restrict__ Tin, float* __restrict__ Tout, int N)
{
    constexpr int SI4 = SI / 4;
    constexpr int DO4 = DO / 4;
    constexpr int PAD = LPN * 4;
    __shared__ float sW[DI * DO];
    __shared__ float sB[PAD];
    int t = threadIdx.x;
    for (int i = t; i < DI * DO; i += 256) sW[i] = W[i];
    for (int i = t; i < PAD; i += 256) sB[i] = (i < DI) ? bias[i] : 0.0f;
    __syncthreads();

    int g = t / LPN;
    int j = t % LPN;
    int n = blockIdx.x * (256 / LPN) + g;
    int nc = (n < N) ? n : (N - 1);
    const int* __restrict__ row = ell + (size_t)nc * ELLW;
    int dg = min(row[0], ELLW - 4);
    if (n >= N) dg = 0;
    float dv = dinv[nc];
    const float4* __restrict__ T4 = (const float4*)Tin;

    float4 a0 = T4[(size_t)nc * SI4 + j];   // self-loop term
    float4 a1 = make_float4(0.f, 0.f, 0.f, 0.f);
    float4 a2 = a1, a3 = a1;
    const int4* __restrict__ rowv = (const int4*)(row + 4);
    int k = 0;
    for (; k + 3 < dg; k += 4) {
        int4 s4 = rowv[k >> 2];
        float4 v0 = T4[(size_t)s4.x * SI4 + j];
        float4 v1 = T4[(size_t)s4.y * SI4 + j];
        float4 v2 = T4[(size_t)s4.z * SI4 + j];
        float4 v3 = T4[(size_t)s4.w * SI4 + j];
        a0.x += v0.x; a0.y += v0.y; a0.z += v0.z; a0.w += v0.w;
        a1.x += v1.x; a1.y += v1.y; a1.z += v1.z; a1.w += v1.w;
        a2.x += v2.x; a2.y += v2.y; a2.z += v2.z; a2.w += v2.w;
        a3.x += v3.x; a3.y += v3.y; a3.z += v3.z; a3.w += v3.w;
    }
    for (; k < dg; ++k) {
        float4 v = T4[(size_t)row[4 + k] * SI4 + j];
        a0.x += v.x; a0.y += v.y; a0.z += v.z; a0.w += v.w;
    }
    float ar[4];
    ar[0] = fmaxf(dv * (a0.x + a1.x + a2.x + a3.x) + sB[4 * j + 0], 0.0f);
    ar[1] = fmaxf(dv * (a0.y + a1.y + a2.y + a3.y) + sB[4 * j + 1], 0.0f);
    ar[2] = fmaxf(dv * (a0.z + a1.z + a2.z + a3.z) + sB[4 * j + 2], 0.0f);
    ar[3] = fmaxf(dv * (a0.w + a1.w + a2.w + a3.w) + sB[4 * j + 3], 0.0f);

    // dense via intra-group shuffle all-to-all (k-th activation = comp k&3 of lane base+(k>>2))
    int lane = t & 63;
    int base = lane - j;
    int jo = (j < DO4) ? j : 0;
    const float4* __restrict__ sW4 = (const float4*)sW;
    float4 o = make_float4(0.f, 0.f, 0.f, 0.f);
#pragma unroll
    for (int k2 = 0; k2 < DI; ++k2) {
        float av = __shfl(ar[k2 & 3], base + (k2 >> 2));
        float4 w = sW4[k2 * DO4 + jo];
        o.x += av * w.x; o.y += av * w.y; o.z += av * w.z; o.w += av * w.w;
    }
    if (n < N && j < DO4)
        ((float4*)Tout)[(size_t)n * DO4 + j] =
            make_float4(dv * o.x, dv * o.y, dv * o.z, dv * o.w);
}

// ---------------- final layer: float4 gather + finalize only (dim 4, 1 lane/node) ----------------
__global__ __launch_bounds__(256) void k_final(
    const int* __restrict__ ell,
    const float* __restrict__ dinv, const float* __restrict__ bias,
    const float* __restrict__ Tin, float* __restrict__ Tout, int N)
{
    int n = blockIdx.x * 256 + threadIdx.x;
    if (n >= N) return;
    const int* __restrict__ row = ell + (size_t)n * ELLW;
    int dg = min(row[0], ELLW - 4);
    float dv = dinv[n];
    const float4* __restrict__ T4 = (const float4*)Tin;

    float4 a0 = T4[n];
    float4 a1 = make_float4(0.f, 0.f, 0.f, 0.f);
    float4 a2 = a1, a3 = a1;
    const int4* __restrict__ rowv = (const int4*)(row + 4);
    int k = 0;
    for (; k + 3 < dg; k += 4) {
        int4 s4 = rowv[k >> 2];
        float4 v0 = T4[s4.x], v1 = T4[s4.y], v2 = T4[s4.z], v3 = T4[s4.w];
        a0.x += v0.x; a0.y += v0.y; a0.z += v0.z; a0.w += v0.w;
        a1.x += v1.x; a1.y += v1.y; a1.z += v1.z; a1.w += v1.w;
        a2.x += v2.x; a2.y += v2.y; a2.z += v2.z; a2.w += v2.w;
        a3.x += v3.x; a3.y += v3.y; a3.z += v3.z; a3.w += v3.w;
    }
    for (; k < dg; ++k) {
        float4 v = T4[row[4 + k]];
        a0.x += v.x; a0.y += v.y; a0.z += v.z; a0.w += v.w;
    }
    float4 b = *(const float4*)bias;
    ((float4*)Tout)[n] = make_float4(
        fmaxf(dv * (a0.x + a1.x + a2.x + a3.x) + b.x, 0.0f),
        fmaxf(dv * (a0.y + a1.y + a2.y + a3.y) + b.y, 0.0f),
        fmaxf(dv * (a0.z + a1.z + a2.z + a3.z) + b.z, 0.0f),
        fmaxf(dv * (a0.w + a1.w + a2.w + a3.w) + b.w, 0.0f));
}

// ---------------- FC: [1000,1200] @ [1200,4] + bias ----------------
__global__ __launch_bounds__(256) void k_fc(
    const float* __restrict__ H, const float* __restrict__ Wfc,
    const float* __restrict__ bfc, float* __restrict__ out)
{
    int r = blockIdx.x;          // 1000 rows
    int t = threadIdx.x;
    float p0 = 0.f, p1 = 0.f, p2 = 0.f, p3 = 0.f;
    for (int k = t; k < 1200; k += 256) {
        float h = H[(size_t)r * 1200 + k];
        p0 += h * Wfc[k * 4 + 0];
        p1 += h * Wfc[k * 4 + 1];
        p2 += h * Wfc[k * 4 + 2];
        p3 += h * Wfc[k * 4 + 3];
    }
#pragma unroll
    for (int off = 32; off > 0; off >>= 1) {
        p0 += __shfl_down(p0, off);
        p1 += __shfl_down(p1, off);
        p2 += __shfl_down(p2, off);
        p3 += __shfl_down(p3, off);
    }
    __shared__ float red[4][4];
    int w = t >> 6, lane = t & 63;
    if (lane == 0) { red[w][0] = p0; red[w][1] = p1; red[w][2] = p2; red[w][3] = p3; }
    __syncthreads();
    if (t < 4) {
        float s = red[0][t] + red[1][t] + red[2][t] + red[3][t];
        out[r * 4 + t] = s + bfc[t];
    }
}

// ---------------------------------------------------------------------------
extern "C" void kernel_launch(void* const* d_in, const int* in_sizes, int n_in,
                              void* d_out, int out_size, void* d_ws, size_t ws_size,
                              hipStream_t stream) {
    const float* x   = (const float*)d_in[0];
    const int*   ei  = (const int*)d_in[1];
    const float* W1  = (const float*)d_in[2];
    const float* b1  = (const float*)d_in[3];
    const float* g1  = (const float*)d_in[4];
    const float* be1 = (const float*)d_in[5];
    const float* m1  = (const float*)d_in[6];
    const float* v1  = (const float*)d_in[7];
    const float* W2  = (const float*)d_in[8];
    const float* b2  = (const float*)d_in[9];
    const float* g2  = (const float*)d_in[10];
    const float* be2 = (const float*)d_in[11];
    const float* m2  = (const float*)d_in[12];
    const float* v2  = (const float*)d_in[13];
    const float* Wc1 = (const float*)d_in[14];
    const float* bc1 = (const float*)d_in[15];
    const float* Wc2 = (const float*)d_in[16];
    const float* bc2 = (const float*)d_in[17];
    const float* Wc3 = (const float*)d_in[18];
    const float* bc3 = (const float*)d_in[19];
    const float* Wc4 = (const float*)d_in[20];
    const float* bc4 = (const float*)d_in[21];
    const float* Wc5 = (const float*)d_in[22];
    const float* bc5 = (const float*)d_in[23];
    const float* Wfc = (const float*)d_in[24];
    const float* bfc = (const float*)d_in[25];

    const int N = in_sizes[0] / 25;          // 300000
    const int E = in_sizes[1] / 2;           // 3000000
    const int NBUCK = (N + NPB - 1) >> BSH2; // 147

    // ---- workspace layout (256B aligned) ----
    char* ws = (char*)d_ws;
    size_t off = 0;
    auto alloc = [&](size_t bytes) { size_t o = off; off += (bytes + 255) & ~(size_t)255; return o; };
    size_t o_flag = alloc(256);
    size_t o_gcnt = alloc((size_t)MAXBK * 4);
    size_t o_prep = alloc(6144 * 4);
    size_t o_dinv = alloc((size_t)N * 4);
    size_t o_ell  = alloc((size_t)N * ELLW * 4);   // 57.6 MB
    size_t o_A = alloc((size_t)N * 32 * 4);        // stride-32 buffer (38.4 MB)
    size_t o_B = alloc((size_t)N * 16 * 4);        // stride-16 buffer (19.2 MB)
    (void)alloc(4096);                             // tail pad

    int*   flag = (int*)(ws + o_flag);
    int*   gcnt = (int*)(ws + o_gcnt);
    float* prep = (float*)(ws + o_prep);
    float* dinv = (float*)(ws + o_dinv);
    int*   ell  = (int*)(ws + o_ell);
    float* A = (float*)(ws + o_A);
    float* B_ = (float*)(ws + o_B);
    int*   bdata = (int*)A;   // 15.7 MB alias: dead before k_ffn writes A (stream-ordered)

    const int B = 256;
    int gN = (N + B - 1) / B;
    int gF = (N + 127) / 128;                // ffn: 128 nodes/block (2 per 4-lane group)
    int gP = (E + 1023) / 1024;

    k_detect<<<1, 64, 0, stream>>>((const unsigned int*)ei, flag);
    hipMemsetAsync(gcnt, 0, (size_t)MAXBK * 4, stream);
    k_prep<<<1, B, 0, stream>>>(W1, b1, g1, be1, m1, v1, W2, b2, g2, be2, m2, v2, Wc1, prep);
    k_part<<<gP, B, 0, stream>>>(ei, flag, gcnt, bdata, E);
    k_ell2<<<NBUCK, B, 0, stream>>>(gcnt, bdata, ell, dinv, N);

    // FFN (prefolded, 2-stage) + dinv scale:  T1 = A (dim 25, stride 32)
    k_ffn<<<gF, B, 0, stream>>>(prep, x, dinv, A, N);
    // L1: gather(25,s32) + bc1 + Wc2 -> B (dim 16)
    k_layer<25, 32, 16, 8><<<(N * 8 + B - 1) / B, B, 0, stream>>>(ell, dinv, bc1, Wc2, A, B_, N);
    // L2: gather(16) + bc2 + Wc3 -> A (dim 16)
    k_layer<16, 16, 16, 4><<<(N * 4 + B - 1) / B, B, 0, stream>>>(ell, dinv, bc2, Wc3, B_, A, N);
    // L3: gather(16) + bc3 + Wc4 -> B (dim 8)
    k_layer<16, 16, 8, 4><<<(N * 4 + B - 1) / B, B, 0, stream>>>(ell, dinv, bc3, Wc4, A, B_, N);
    // L4: gather(8) + bc4 + Wc5 -> A (dim 4)
    k_layer<8, 8, 4, 2><<<(N * 2 + B - 1) / B, B, 0, stream>>>(ell, dinv, bc4, Wc5, B_, A, N);
    // L5: gather(4) + bc5 + relu -> B (dim 4, final node features)
    k_final<<<gN, B, 0, stream>>>(ell, dinv, bc5, A, B_, N);
    // FC
    k_fc<<<1000, B, 0, stream>>>(B_, Wfc, bfc, (float*)d_out);
}

// Round 12
// 522.193 us; speedup vs baseline: 1.1687x; 1.1062x over previous
//
#include <hip/hip_runtime.h>

#define BN_EPS 1e-5f
#define ELLW 48      // slot 0 = count, slots 4..47 = neighbor ids (16B-aligned), cap 44 >> max deg ~33
#define BSH2 11      // bucket = dst >> 11  (2048 nodes per bucket)
#define NPB 2048
#define MAXBK 160    // compile-time bound on bucket count (N <= 327680)
#define BCAP2 26624  // per-bucket edge capacity (mean ~20.4K, +43 sigma)

// ---------------- detect int64 vs int32 edge_index ----------------
__global__ void k_detect(const unsigned int* __restrict__ ei, int* __restrict__ flag) {
    int t = threadIdx.x;                 // 64 threads, one wave
    unsigned int v = ei[2 * t + 1];      // odd words: int64 high-halves (==0) or real int32 values
    unsigned long long mask = __ballot(v != 0);
    if (t == 0) flag[0] = (mask == 0ULL) ? 1 : 0;   // 1 => int64
}

// ---------------- pass 1: block-grouped partition by dst>>11 ----------------
__global__ __launch_bounds__(256) void k_part(
    const int* __restrict__ ei, const int* __restrict__ flag,
    int* __restrict__ gcnt, int* __restrict__ bdata, int E)
{
    __shared__ int hist[MAXBK];
    __shared__ int cur[MAXBK];
    __shared__ int gbase[MAXBK];
    __shared__ int locstart[MAXBK + 1];
    __shared__ int sc[256];
    __shared__ int stage[1024];

    int t = threadIdx.x;
    int blockBase = blockIdx.x * 1024;
    int blockCnt = E - blockBase; if (blockCnt > 1024) blockCnt = 1024; if (blockCnt < 0) blockCnt = 0;

    for (int i = t; i < MAXBK; i += 256) hist[i] = 0;
    __syncthreads();

    bool w64 = (flag[0] != 0);
    int e = blockBase + t * 4;
    int s[4], d[4];
    int cnt = 0;
    if (e < E) {
        cnt = E - e; if (cnt > 4) cnt = 4;
        if (cnt == 4) {
            if (w64) {
                const int4* ps = (const int4*)(ei + (size_t)2 * e);
                int4 a = ps[0], b = ps[1];
                s[0] = a.x; s[1] = a.z; s[2] = b.x; s[3] = b.z;
                const int4* pd = (const int4*)(ei + (size_t)2 * ((size_t)E + e));
                int4 c = pd[0], f = pd[1];
                d[0] = c.x; d[1] = c.z; d[2] = f.x; d[3] = f.z;
            } else {
                int4 a = *(const int4*)(ei + e);
                s[0] = a.x; s[1] = a.y; s[2] = a.z; s[3] = a.w;
                int4 c = *(const int4*)(ei + (size_t)E + e);
                d[0] = c.x; d[1] = c.y; d[2] = c.z; d[3] = c.w;
            }
        } else {
            for (int i = 0; i < cnt; ++i) {
                if (w64) { s[i] = ei[(size_t)2 * (e + i)]; d[i] = ei[(size_t)2 * ((size_t)E + e + i)]; }
                else     { s[i] = ei[e + i];               d[i] = ei[(size_t)E + e + i]; }
            }
        }
    }
    int bk[4], pk[4];
    for (int i = 0; i < cnt; ++i) {
        bk[i] = d[i] >> BSH2;
        pk[i] = (s[i] << BSH2) | (d[i] & (NPB - 1));
        atomicAdd(&hist[bk[i]], 1);
    }
    __syncthreads();

    // inclusive scan over MAXBK (padded to 256)
    sc[t] = (t < MAXBK) ? hist[t] : 0;
    __syncthreads();
    for (int off = 1; off < 256; off <<= 1) {
        int x = (t >= off) ? sc[t - off] : 0;
        __syncthreads();
        sc[t] += x;
        __syncthreads();
    }
    if (t < MAXBK) {
        locstart[t] = sc[t] - hist[t];
        cur[t] = sc[t] - hist[t];
        if (hist[t] > 0) gbase[t] = atomicAdd(&gcnt[t], hist[t]);
    }
    if (t == 255) locstart[MAXBK] = sc[MAXBK - 1];
    __syncthreads();

    // stage grouped by bucket
    for (int i = 0; i < cnt; ++i) {
        int p = atomicAdd(&cur[bk[i]], 1);
        stage[p] = pk[i];
    }
    __syncthreads();

    // copy groups out contiguously
    for (int sIdx = t; sIdx < blockCnt; sIdx += 256) {
        int lo = 0, hi = MAXBK;
        while (hi - lo > 1) {
            int mid = (lo + hi) >> 1;
            if (locstart[mid] <= sIdx) lo = mid; else hi = mid;
        }
        int g = gbase[lo] + (sIdx - locstart[lo]);
        if (g < BCAP2) bdata[(size_t)lo * BCAP2 + g] = stage[sIdx];
    }
}

// ---------------- pass 2: one block per bucket; LDS slot alloc; write ELL + count + dinv ----------------
__global__ __launch_bounds__(256) void k_ell2(
    const int* __restrict__ gcnt, const int* __restrict__ bdata,
    int* __restrict__ ell, float* __restrict__ dinv, int N)
{
    __shared__ int lcnt[NPB];
    int b = blockIdx.x;
    int t = threadIdx.x;
    for (int i = t; i < NPB; i += 256) lcnt[i] = 0;
    __syncthreads();
    int base = b << BSH2;
    int cnt = min(gcnt[b], BCAP2);
    const int* __restrict__ bd = bdata + (size_t)b * BCAP2;
    for (int i = t; i < cnt; i += 256) {
        int v = bd[i];
        int dl = v & (NPB - 1);
        int src = v >> BSH2;                      // v < 2^30, arithmetic shift fine
        int pos = atomicAdd(&lcnt[dl], 1);
        if (pos < ELLW - 4)
            ell[(size_t)(base + dl) * ELLW + 4 + pos] = src;
    }
    __syncthreads();
    for (int i = t; i < NPB; i += 256) {
        int n = base + i;
        if (n < N) {
            int c = lcnt[i];
            ell[(size_t)n * ELLW] = c;
            dinv[n] = 1.0f / sqrtf((float)(c + 1));   // +1 self-loop
        }
    }
}

// ---------------- prep: fold BN scales + (W2'@Wc1) off the hot path ----------------
// prep layout: [0,2800): W1f [kc*25+j][28];  [2800,5600): W2c [k][28];
//              [5600,5700): B1f;  [5704,5736): bvec (b2''@Wc1, pad 32)
__global__ __launch_bounds__(256) void k_prep(
    const float* __restrict__ W1, const float* __restrict__ b1,
    const float* __restrict__ g1, const float* __restrict__ be1,
    const float* __restrict__ m1, const float* __restrict__ v1,
    const float* __restrict__ W2, const float* __restrict__ b2,
    const float* __restrict__ g2, const float* __restrict__ be2,
    const float* __restrict__ m2, const float* __restrict__ v2,
    const float* __restrict__ Wc1, float* __restrict__ prep)
{
    __shared__ float s1[100], bb1[100], s2[25], bb2[25], wc[625];
    int t = threadIdx.x;
    if (t < 100) {
        float s = g1[t] * rsqrtf(v1[t] + BN_EPS);
        s1[t] = s; bb1[t] = (b1[t] - m1[t]) * s + be1[t];
    }
    if (t >= 128 && t < 153) {
        int u = t - 128;
        float s = g2[u] * rsqrtf(v2[u] + BN_EPS);
        s2[u] = s; bb2[u] = (b2[u] - m2[u]) * s + be2[u];
    }
    for (int q = t; q < 625; q += 256) wc[q] = Wc1[q];
    __syncthreads();
    for (int q = t; q < 2800; q += 256) {
        int row = q / 28, kk = q % 28;        // row = kc*25+j
        int kc = row / 25, j = row % 25;
        prep[q] = (kk < 25) ? W1[j * 100 + kc * 25 + kk] * s1[kc * 25 + kk] : 0.0f;
    }
    for (int q = t; q < 2800; q += 256) {
        int k = q / 28, j = q % 28;
        float acc = 0.0f;
        if (j < 25)
            for (int m = 0; m < 25; ++m) acc += W2[k * 25 + m] * s2[m] * wc[m * 25 + j];
        prep[2800 + q] = acc;
    }
    if (t < 100) prep[5600 + t] = bb1[t];
    if (t >= 128 && t < 160) {
        int j = t - 128;
        float acc = 0.0f;
        if (j < 25)
            for (int m = 0; m < 25; ++m) acc += bb2[m] * wc[m * 25 + j];
        prep[5704 + j] = acc;
    }
}

// ---------------- fused FFN (2-stage, prefolded) + dinv scale; out stride 32 ----------------
// 4 lanes per node, 2 nodes per group (M-block x2): lane l owns hidden chunk l*25..l*25+24.
// launch_bounds(256,2): VGPR cap 128 >= ~115 live -> NO spills (cap 84 at (256,3) spilled to scratch).
__global__ __launch_bounds__(256, 2) void k_ffn(
    const float* __restrict__ prep, const float* __restrict__ x,
    const float* __restrict__ dinv, float* __restrict__ T, int N)
{
    __shared__ float sW1[2800];
    __shared__ float sW2c[2800];
    __shared__ float sB1[100];
    __shared__ float sBv[32];
    int t = threadIdx.x;
    for (int q = t; q < 2800; q += 256) sW1[q] = prep[q];
    for (int q = t; q < 2800; q += 256) sW2c[q] = prep[2800 + q];
    if (t < 100) sB1[t] = prep[5600 + t];
    if (t >= 128 && t < 160) sBv[t - 128] = prep[5704 + (t - 128)];
    __syncthreads();

    int g = t >> 2, l = t & 3;
    int n0 = ((int)blockIdx.x * 64 + g) * 2;
    if (n0 >= N) return;
    bool two = (n0 + 1 < N);
    int n1 = two ? n0 + 1 : n0;

    float xiA[25], xiB[25];
#pragma unroll
    for (int j = 0; j < 25; ++j) xiA[j] = x[(size_t)n0 * 25 + j];
#pragma unroll
    for (int j = 0; j < 25; ++j) xiB[j] = x[(size_t)n1 * 25 + j];

    // stage 1: hidden chunk l*25..l*25+24 for both nodes (shared weight reads)
    float hmA[25], hmB[25];
#pragma unroll
    for (int kk = 0; kk < 25; ++kk) { hmA[kk] = sB1[l * 25 + kk]; hmB[kk] = hmA[kk]; }
#pragma unroll
    for (int j = 0; j < 25; ++j) {
        float xa = xiA[j], xb = xiB[j];
        const float* __restrict__ wr = &sW1[(l * 25 + j) * 28];
#pragma unroll
        for (int kk = 0; kk < 25; ++kk) {
            float w = wr[kk];
            hmA[kk] += xa * w;
            hmB[kk] += xb * w;
        }
    }

    // stage 2: partial o (over own hidden chunk) through folded W2c
    float oA[25], oB[25];
#pragma unroll
    for (int j = 0; j < 25; ++j) { oA[j] = 0.0f; oB[j] = 0.0f; }
#pragma unroll
    for (int kk = 0; kk < 25; ++kk) {
        float ra = fmaxf(hmA[kk], 0.0f);
        float rb = fmaxf(hmB[kk], 0.0f);
        const float* __restrict__ wr = &sW2c[(l * 25 + kk) * 28];
#pragma unroll
        for (int j = 0; j < 25; ++j) {
            float w = wr[j];
            oA[j] += ra * w;
            oB[j] += rb * w;
        }
    }

    // slice-wise reduce across the 4-lane group; lane l keeps slice l (static indices only)
    float dvA = dinv[n0], dvB = dinv[n1];
    float outA[8], outB[8];
#pragma unroll
    for (int jj = 0; jj < 8; ++jj) { outA[jj] = 0.0f; outB[jj] = 0.0f; }
#pragma unroll
    for (int s = 0; s < 4; ++s) {
#pragma unroll
        for (int jj = 0; jj < 8; ++jj) {
            int j = s * 8 + jj;
            if (j < 25) {
                float va = oA[j];
                va += __shfl_xor(va, 1); va += __shfl_xor(va, 2);
                float vb = oB[j];
                vb += __shfl_xor(vb, 1); vb += __shfl_xor(vb, 2);
                if (l == s) {
                    outA[jj] = (va + sBv[j]) * dvA;
                    outB[jj] = (vb + sBv[j]) * dvB;
                }
            }
        }
    }

    float4* TA = (float4*)(T + (size_t)n0 * 32 + l * 8);
    TA[0] = make_float4(outA[0], outA[1], outA[2], outA[3]);
    TA[1] = make_float4(outA[4], outA[5], outA[6], outA[7]);
    if (two) {
        float4* TB = (float4*)(T + (size_t)n1 * 32 + l * 8);
        TB[0] = make_float4(outB[0], outB[1], outB[2], outB[3]);
        TB[1] = make_float4(outB[4], outB[5], outB[6], outB[7]);
    }
}

// ---------------- fused layer: float4 gather (ELL) + finalize + dense + scale ----------------
// LPN = lanes/node, each lane owns 4 features. SI = input stride (floats, mult of 4).
template <int DI, int SI, int DO, int LPN>
__global__ __launch_bounds__(256) void k_layer(
    const int* __restrict__ ell,
    const float* __restrict__ dinv, const float* __restrict__ bias,   // bias: [DI]
    const float* __restrict__ W,                                      // [DI x DO]
    const float* __restrict__ Tin, float* __restrict__ Tout, int N)
{
    constexpr int SI4 = SI / 4;
    constexpr int DO4 = DO / 4;
    constexpr int PAD = LPN * 4;
    __shared__ float sW[DI * DO];
    __shared__ float sB[PAD];
    int t = threadIdx.x;
    for (int i = t; i < DI * DO; i += 256) sW[i] = W[i];
    for (int i = t; i < PAD; i += 256) sB[i] = (i < DI) ? bias[i] : 0.0f;
    __syncthreads();

    int g = t / LPN;
    int j = t % LPN;
    int n = blockIdx.x * (256 / LPN) + g;
    int nc = (n < N) ? n : (N - 1);
    const int* __restrict__ row = ell + (size_t)nc * ELLW;
    int dg = min(row[0], ELLW - 4);
    if (n >= N) dg = 0;
    float dv = dinv[nc];
    const float4* __restrict__ T4 = (const float4*)Tin;

    float4 a0 = T4[(size_t)nc * SI4 + j];   // self-loop term
    float4 a1 = make_float4(0.f, 0.f, 0.f, 0.f);
    float4 a2 = a1, a3 = a1;
    const int4* __restrict__ rowv = (const int4*)(row + 4);
    int k = 0;
    for (; k + 3 < dg; k += 4) {
        int4 s4 = rowv[k >> 2];
        float4 v0 = T4[(size_t)s4.x * SI4 + j];
        float4 v1 = T4[(size_t)s4.y * SI4 + j];
        float4 v2 = T4[(size_t)s4.z * SI4 + j];
        float4 v3 = T4[(size_t)s4.w * SI4 + j];
        a0.x += v0.x; a0.y += v0.y; a0.z += v0.z; a0.w += v0.w;
        a1.x += v1.x; a1.y += v1.y; a1.z += v1.z; a1.w += v1.w;
        a2.x += v2.x; a2.y += v2.y; a2.z += v2.z; a2.w += v2.w;
        a3.x += v3.x; a3.y += v3.y; a3.z += v3.z; a3.w += v3.w;
    }
    for (; k < dg; ++k) {
        float4 v = T4[(size_t)row[4 + k] * SI4 + j];
        a0.x += v.x; a0.y += v.y; a0.z += v.z; a0.w += v.w;
    }
    float ar[4];
    ar[0] = fmaxf(dv * (a0.x + a1.x + a2.x + a3.x) + sB[4 * j + 0], 0.0f);
    ar[1] = fmaxf(dv * (a0.y + a1.y + a2.y + a3.y) + sB[4 * j + 1], 0.0f);
    ar[2] = fmaxf(dv * (a0.z + a1.z + a2.z + a3.z) + sB[4 * j + 2], 0.0f);
    ar[3] = fmaxf(dv * (a0.w + a1.w + a2.w + a3.w) + sB[4 * j + 3], 0.0f);

    // dense via intra-group shuffle all-to-all (k-th activation = comp k&3 of lane base+(k>>2))
    int lane = t & 63;
    int base = lane - j;
    int jo = (j < DO4) ? j : 0;
    const float4* __restrict__ sW4 = (const float4*)sW;
    float4 o = make_float4(0.f, 0.f, 0.f, 0.f);
#pragma unroll
    for (int k2 = 0; k2 < DI; ++k2) {
        float av = __shfl(ar[k2 & 3], base + (k2 >> 2));
        float4 w = sW4[k2 * DO4 + jo];
        o.x += av * w.x; o.y += av * w.y; o.z += av * w.z; o.w += av * w.w;
    }
    if (n < N && j < DO4)
        ((float4*)Tout)[(size_t)n * DO4 + j] =
            make_float4(dv * o.x, dv * o.y, dv * o.z, dv * o.w);
}

// ---------------- final layer: float4 gather + finalize only (dim 4, 1 lane/node) ----------------
__global__ __launch_bounds__(256) void k_final(
    const int* __restrict__ ell,
    const float* __restrict__ dinv, const float* __restrict__ bias,
    const float* __restrict__ Tin, float* __restrict__ Tout, int N)
{
    int n = blockIdx.x * 256 + threadIdx.x;
    if (n >= N) return;
    const int* __restrict__ row = ell + (size_t)n * ELLW;
    int dg = min(row[0], ELLW - 4);
    float dv = dinv[n];
    const float4* __restrict__ T4 = (const float4*)Tin;

    float4 a0 = T4[n];
    float4 a1 = make_float4(0.f, 0.f, 0.f, 0.f);
    float4 a2 = a1, a3 = a1;
    const int4* __restrict__ rowv = (const int4*)(row + 4);
    int k = 0;
    for (; k + 3 < dg; k += 4) {
        int4 s4 = rowv[k >> 2];
        float4 v0 = T4[s4.x], v1 = T4[s4.y], v2 = T4[s4.z], v3 = T4[s4.w];
        a0.x += v0.x; a0.y += v0.y; a0.z += v0.z; a0.w += v0.w;
        a1.x += v1.x; a1.y += v1.y; a1.z += v1.z; a1.w += v1.w;
        a2.x += v2.x; a2.y += v2.y; a2.z += v2.z; a2.w += v2.w;
        a3.x += v3.x; a3.y += v3.y; a3.z += v3.z; a3.w += v3.w;
    }
    for (; k < dg; ++k) {
        float4 v = T4[row[4 + k]];
        a0.x += v.x; a0.y += v.y; a0.z += v.z; a0.w += v.w;
    }
    float4 b = *(const float4*)bias;
    ((float4*)Tout)[n] = make_float4(
        fmaxf(dv * (a0.x + a1.x + a2.x + a3.x) + b.x, 0.0f),
        fmaxf(dv * (a0.y + a1.y + a2.y + a3.y) + b.y, 0.0f),
        fmaxf(dv * (a0.z + a1.z + a2.z + a3.z) + b.z, 0.0f),
        fmaxf(dv * (a0.w + a1.w + a2.w + a3.w) + b.w, 0.0f));
}

// ---------------- FC: [1000,1200] @ [1200,4] + bias ----------------
__global__ __launch_bounds__(256) void k_fc(
    const float* __restrict__ H, const float* __restrict__ Wfc,
    const float* __restrict__ bfc, float* __restrict__ out)
{
    int r = blockIdx.x;          // 1000 rows
    int t = threadIdx.x;
    float p0 = 0.f, p1 = 0.f, p2 = 0.f, p3 = 0.f;
    for (int k = t; k < 1200; k += 256) {
        float h = H[(size_t)r * 1200 + k];
        p0 += h * Wfc[k * 4 + 0];
        p1 += h * Wfc[k * 4 + 1];
        p2 += h * Wfc[k * 4 + 2];
        p3 += h * Wfc[k * 4 + 3];
    }
#pragma unroll
    for (int off = 32; off > 0; off >>= 1) {
        p0 += __shfl_down(p0, off);
        p1 += __shfl_down(p1, off);
        p2 += __shfl_down(p2, off);
        p3 += __shfl_down(p3, off);
    }
    __shared__ float red[4][4];
    int w = t >> 6, lane = t & 63;
    if (lane == 0) { red[w][0] = p0; red[w][1] = p1; red[w][2] = p2; red[w][3] = p3; }
    __syncthreads();
    if (t < 4) {
        float s = red[0][t] + red[1][t] + red[2][t] + red[3][t];
        out[r * 4 + t] = s + bfc[t];
    }
}

// ---------------------------------------------------------------------------
extern "C" void kernel_launch(void* const* d_in, const int* in_sizes, int n_in,
                              void* d_out, int out_size, void* d_ws, size_t ws_size,
                              hipStream_t stream) {
    const float* x   = (const float*)d_in[0];
    const int*   ei  = (const int*)d_in[1];
    const float* W1  = (const float*)d_in[2];
    const float* b1  = (const float*)d_in[3];
    const float* g1  = (const float*)d_in[4];
    const float* be1 = (const float*)d_in[5];
    const float* m1  = (const float*)d_in[6];
    const float* v1  = (const float*)d_in[7];
    const float* W2  = (const float*)d_in[8];
    const float* b2  = (const float*)d_in[9];
    const float* g2  = (const float*)d_in[10];
    const float* be2 = (const float*)d_in[11];
    const float* m2  = (const float*)d_in[12];
    const float* v2  = (const float*)d_in[13];
    const float* Wc1 = (const float*)d_in[14];
    const float* bc1 = (const float*)d_in[15];
    const float* Wc2 = (const float*)d_in[16];
    const float* bc2 = (const float*)d_in[17];
    const float* Wc3 = (const float*)d_in[18];
    const float* bc3 = (const float*)d_in[19];
    const float* Wc4 = (const float*)d_in[20];
    const float* bc4 = (const float*)d_in[21];
    const float* Wc5 = (const float*)d_in[22];
    const float* bc5 = (const float*)d_in[23];
    const float* Wfc = (const float*)d_in[24];
    const float* bfc = (const float*)d_in[25];

    const int N = in_sizes[0] / 25;          // 300000
    const int E = in_sizes[1] / 2;           // 3000000
    const int NBUCK = (N + NPB - 1) >> BSH2; // 147

    // ---- workspace layout (256B aligned) ----
    char* ws = (char*)d_ws;
    size_t off = 0;
    auto alloc = [&](size_t bytes) { size_t o = off; off += (bytes + 255) & ~(size_t)255; return o; };
    size_t o_flag = alloc(256);
    size_t o_gcnt = alloc((size_t)MAXBK * 4);
    size_t o_prep = alloc(6144 * 4);
    size_t o_dinv = alloc((size_t)N * 4);
    size_t o_ell  = alloc((size_t)N * ELLW * 4);   // 57.6 MB
    size_t o_A = alloc((size_t)N * 32 * 4);        // stride-32 buffer (38.4 MB)
    size_t o_B = alloc((size_t)N * 16 * 4);        // stride-16 buffer (19.2 MB)
    (void)alloc(4096);                             // tail pad

    int*   flag = (int*)(ws + o_flag);
    int*   gcnt = (int*)(ws + o_gcnt);
    float* prep = (float*)(ws + o_prep);
    float* dinv = (float*)(ws + o_dinv);
    int*   ell  = (int*)(ws + o_ell);
    float* A = (float*)(ws + o_A);
    float* B_ = (float*)(ws + o_B);
    int*   bdata = (int*)A;   // 15.7 MB alias: dead before k_ffn writes A (stream-ordered)

    const int B = 256;
    int gN = (N + B - 1) / B;
    int gF = (N + 127) / 128;                // ffn: 128 nodes/block (2 per 4-lane group)
    int gP = (E + 1023) / 1024;

    k_detect<<<1, 64, 0, stream>>>((const unsigned int*)ei, flag);
    hipMemsetAsync(gcnt, 0, (size_t)MAXBK * 4, stream);
    k_prep<<<1, B, 0, stream>>>(W1, b1, g1, be1, m1, v1, W2, b2, g2, be2, m2, v2, Wc1, prep);
    k_part<<<gP, B, 0, stream>>>(ei, flag, gcnt, bdata, E);
    k_ell2<<<NBUCK, B, 0, stream>>>(gcnt, bdata, ell, dinv, N);

    // FFN (prefolded, 2-stage) + dinv scale:  T1 = A (dim 25, stride 32)
    k_ffn<<<gF, B, 0, stream>>>(prep, x, dinv, A, N);
    // L1: gather(25,s32) + bc1 + Wc2 -> B (dim 16)
    k_layer<25, 32, 16, 8><<<(N * 8 + B - 1) / B, B, 0, stream>>>(ell, dinv, bc1, Wc2, A, B_, N);
    // L2: gather(16) + bc2 + Wc3 -> A (dim 16)
    k_layer<16, 16, 16, 4><<<(N * 4 + B - 1) / B, B, 0, stream>>>(ell, dinv, bc2, Wc3, B_, A, N);
    // L3: gather(16) + bc3 + Wc4 -> B (dim 8)
    k_layer<16, 16, 8, 4><<<(N * 4 + B - 1) / B, B, 0, stream>>>(ell, dinv, bc3, Wc4, A, B_, N);
    // L4: gather(8) + bc4 + Wc5 -> A (dim 4)
    k_layer<8, 8, 4, 2><<<(N * 2 + B - 1) / B, B, 0, stream>>>(ell, dinv, bc4, Wc5, B_, A, N);
    // L5: gather(4) + bc5 + relu -> B (dim 4, final node features)
    k_final<<<gN, B, 0, stream>>>(ell, dinv, bc5, A, B_, N);
    // FC
    k_fc<<<1000, B, 0, stream>>>(B_, Wfc, bfc, (float*)d_out);
}